// Round 4
// baseline (92.587 us; speedup 1.0000x reference)
//
#include <hip/hip_runtime.h>
#include <stdint.h>

#define B_N    16384
#define F_N    512
#define NPAIR  128            // 256 steps (1 pad + 255 sites) fused into 128 pairs per side
#define CHUNKP 4              // pairs per staged chunk
#define NCHUNKC (NPAIR/CHUNKP)

typedef float    f32x16 __attribute__((ext_vector_type(16)));
typedef short    s16x8  __attribute__((ext_vector_type(8)));
typedef int      i32x4  __attribute__((ext_vector_type(4)));

// ws layout (shorts): left pair-frags [0,262144), right [262144,524288),
// M (256 f32) at short 524288, c0 at short 524800.
// per pair-side: 2048 shorts = [A1hi(512)|A1lo(512)|A2hi(512)|A2lo(512)]
#define WS_SIDE_STRIDE 262144
#define WS_BYTES_NEEDED ((524800 + 2) * 2)

static __device__ __forceinline__ void split_pack8(const float* f, unsigned* ph, unsigned* pl) {
#pragma unroll
  for (int j = 0; j < 4; ++j) {
    float f0 = f[2*j], f1 = f[2*j+1];
    unsigned u0 = __float_as_uint(f0), u1 = __float_as_uint(f1);
    ph[j] = __builtin_amdgcn_perm(u1, u0, 0x07060302u);
    float l0 = f0 - __uint_as_float(u0 & 0xffff0000u);
    float l1 = f1 - __uint_as_float(u1 & 0xffff0000u);
    pl[j] = __builtin_amdgcn_perm(__float_as_uint(l1), __float_as_uint(l0), 0x07060302u);
  }
}

static __device__ __forceinline__ s16x8 as_s16x8(const unsigned* p) {
  i32x4 v; v.x = (int)p[0]; v.y = (int)p[1]; v.z = (int)p[2]; v.w = (int)p[3];
  return __builtin_bit_cast(s16x8, v);
}

// sigma: output-row permutation (swap row bits 2<->3 within each 16-row block) so that
// MFMA D-regs land in natural v-order: reg r, lane-half h holds v''[8h + r]. No permlanes.
static __device__ __forceinline__ int tau(int m) {
  return (m & 3) | ((m & 4) << 1) | ((m & 8) >> 1);
}

// ---------------- prep: fuse site pairs into 4 product matrices, emit MFMA A-frags ----
// Left pair p: v'' = [P00 + xa P10 + xb P01 + xa xb P11]^T v; A1=[P00^T;P10^T], A2=[P01^T;P11^T]
// Right pair p: u'' = [R00 + xa R10 + xb R01 + xa xb R11] u; A1=[R00;R10], A2=[R01;R11]
// A-frag layout (32x32x16): lane l holds A[m=l&31][k=8*(l>>5)+i], i=0..7; rows tau-permuted.
__global__ __launch_bounds__(256) void mps_prep(
    const float* __restrict__ W0, const float* __restrict__ W_left,
    const float* __restrict__ W_out, const float* __restrict__ W_right,
    const float* __restrict__ WN, const float* __restrict__ d1_w,
    const float* __restrict__ d1_b, const float* __restrict__ d2_w,
    const float* __restrict__ d2_b, unsigned short* __restrict__ ws)
{
  int bid = blockIdx.x;
  if (bid < 256) {
    int side = bid >> 7;
    int pair = bid & 127;
    __shared__ float Wa[512];    // [d*32 + p*16 + m]
    __shared__ float Wb[512];
    __shared__ float Af[1024];   // A1[32][16] | A2[32][16]  (tau-permuted rows)
    int t = threadIdx.x;
    bool pad_a = (pair == 0);
    const float* base_a = side ? (W_right + (size_t)(255 - 2*pair) * 512)
                               : (W_left  + (size_t)(2*pair - 1) * 512);
    const float* base_b = side ? (W_right + (size_t)(254 - 2*pair) * 512)
                               : (W_left  + (size_t)(2*pair) * 512);
#pragma unroll
    for (int e = t; e < 512; e += 256) {
      float va;
      if (pad_a) { int d = e >> 5, p = (e >> 4) & 1, m = e & 15; va = (p == 0 && d == m) ? 1.f : 0.f; }
      else va = base_a[e];
      Wa[e] = va;
      Wb[e] = base_b[e];
    }
    __syncthreads();
#pragma unroll
    for (int ei = t; ei < 1024; ei += 256) {
      int amat = ei >> 9;          // 0: A1, 1: A2 (phys idx of site b)
      int rem  = ei & 511;
      int m32  = rem >> 4;
      int k    = rem & 15;
      int pa   = m32 >> 4;         // phys idx of site a (stacked block)
      int m    = tau(m32 & 15);    // tau-permuted output row
      float acc = 0.f;
      if (side == 0) {
#pragma unroll
        for (int j = 0; j < 16; ++j) acc += Wa[k*32 + pa*16 + j] * Wb[j*32 + amat*16 + m];
      } else {
#pragma unroll
        for (int j = 0; j < 16; ++j) acc += Wb[m*32 + amat*16 + j] * Wa[j*32 + pa*16 + k];
      }
      Af[ei] = acc;
    }
    __syncthreads();
    {
      int f = t >> 6, l = t & 63;          // f: 0=A1hi 1=A1lo 2=A2hi 3=A2lo
      int amat = f >> 1, lo = f & 1;
      int m32 = l & 31, kb = (l >> 5) * 8;
      s16x8 v8;
#pragma unroll
      for (int i = 0; i < 8; ++i) {
        float w = Af[amat*512 + m32*16 + kb + i];
        unsigned u = __float_as_uint(w);
        unsigned short h = (unsigned short)(u >> 16);
        if (lo) {
          float rl = w - __uint_as_float((unsigned)h << 16);
          h = (unsigned short)(__float_as_uint(rl) >> 16);
        }
        v8[i] = (short)h;
      }
      *reinterpret_cast<s16x8*>(ws + (size_t)side * WS_SIDE_STRIDE
                                   + (size_t)pair * 2048 + f * 512 + l * 8) = v8;
    }
  } else {
    // M[d][e] = sum_o wef[o] * W_out[d][o][e];  c0 = d2_b + sum_h d2_w[h] d1_b[h]
    int t = threadIdx.x;
    int d = t >> 4, e = t & 15;
    float acc = 0.f;
#pragma unroll
    for (int o = 0; o < 8; ++o) {
      float wef = 0.f;
      for (int hh = 0; hh < 24; ++hh) wef += d2_w[hh] * d1_w[hh*8 + o];
      acc += wef * W_out[d*128 + o*16 + e];
    }
    float* wf = reinterpret_cast<float*>(ws);
    wf[262144 + t] = acc;
    if (t == 0) {
      float c0 = d2_b[0];
      for (int hh = 0; hh < 24; ++hh) c0 += d2_w[hh] * d1_b[hh];
      wf[262400] = c0;
    }
  }
}

// ---------------- main: 2 waves/block {L,R}, 64 samples each (2 independent chains), 256 blocks
__global__ __launch_bounds__(128, 1) void mps_main(
    const float* __restrict__ x, const float* __restrict__ W0,
    const float* __restrict__ WN, const unsigned short* __restrict__ ws,
    float* __restrict__ out)
{
  __shared__ __align__(16) unsigned short sbuf[2][2][CHUNKP][4][64][8]; // 64 KiB
  __shared__ float fin[2][64][16];                                      // 8 KiB

  const int tidx = threadIdx.x;
  const int side = tidx >> 6;        // wave 0 = left chain, wave 1 = right chain
  const int lane = tidx & 63;
  const int col  = lane & 31;
  const int h    = lane >> 5;
  const float* xA = x + (size_t)(blockIdx.x * 64 + col) * F_N;       // chain A sample
  const float* xB = xA + (size_t)32 * F_N;                           // chain B sample
  const unsigned short* frag = ws + (size_t)side * WS_SIDE_STRIDE;

  // init states in natural B-layout: lane-half h holds v0[8h+i]
  unsigned vhiA[4], vloA[4], vhiB[4], vloB[4];
  {
    float a0[8], a1[8], f0[8];
#pragma unroll
    for (int i = 0; i < 8; ++i) {
      int idx = h*8 + i;
      a0[i] = side ? WN[idx*2]   : W0[idx];
      a1[i] = side ? WN[idx*2+1] : W0[16+idx];
    }
    float xiA = side ? xA[F_N-1] : xA[0];
    float xiB = side ? xB[F_N-1] : xB[0];
#pragma unroll
    for (int i = 0; i < 8; ++i) f0[i] = fmaf(xiA, a1[i], a0[i]);
    split_pack8(f0, vhiA, vloA);
#pragma unroll
    for (int i = 0; i < 8; ++i) f0[i] = fmaf(xiB, a1[i], a0[i]);
    split_pack8(f0, vhiB, vloB);
  }

  f32x16 Dz;
#pragma unroll
  for (int i = 0; i < 16; ++i) Dz[i] = 0.f;

  auto stage = [&](int chunk, int db) {
    const unsigned short* gs = frag + (size_t)chunk * (CHUNKP * 2048);
#pragma unroll
    for (int s2 = 0; s2 < 16; ++s2) {
      int pr = s2 >> 2, fg = s2 & 3;
      __builtin_amdgcn_global_load_lds(
        (const __attribute__((address_space(1))) void*)(gs + pr*2048 + fg*512 + lane*8),
        (__attribute__((address_space(3))) void*)(&sbuf[side][db][pr][fg][0][0]),
        16, 0, 0);
    }
  };

  auto xp0 = [&](const float* xr, int c) { return xr + (side ? (504 - 8*c) : (8*c)); };
  auto xp1 = [&](const float* xr, int c) { return xr + (side ? (508 - 8*c) : (8*c + 4)); };

  float4 xcA0 = *reinterpret_cast<const float4*>(xp0(xA, 0));
  float4 xcA1 = *reinterpret_cast<const float4*>(xp1(xA, 0));
  float4 xcB0 = *reinterpret_cast<const float4*>(xp0(xB, 0));
  float4 xcB1 = *reinterpret_cast<const float4*>(xp1(xB, 0));

  stage(0, 0);
  asm volatile("s_waitcnt vmcnt(0)" ::: "memory");   // own-wave staging only: no barrier needed

  float dcombA[8], dcombB[8];
#pragma unroll 1
  for (int c = 0; c < NCHUNKC; ++c) {
    float4 xnA0 = xcA0, xnA1 = xcA1, xnB0 = xcB0, xnB1 = xcB1;
    if (c + 1 < NCHUNKC) {
      stage(c + 1, (c + 1) & 1);
      xnA0 = *reinterpret_cast<const float4*>(xp0(xA, c + 1));
      xnA1 = *reinterpret_cast<const float4*>(xp1(xA, c + 1));
      xnB0 = *reinterpret_cast<const float4*>(xp0(xB, c + 1));
      xnB1 = *reinterpret_cast<const float4*>(xp1(xB, c + 1));
    }
    const unsigned short* lb = &sbuf[side][c & 1][0][0][0][0];
    s16x8 fr[16];
#pragma unroll
    for (int i = 0; i < 16; ++i)
      fr[i] = *reinterpret_cast<const s16x8*>(lb + i*512 + lane*8);

#pragma unroll
    for (int p4 = 0; p4 < 4; ++p4) {
      float xaA, xbA, xaB, xbB;
      if (side == 0) {
        xaA = (p4 == 0) ? xcA0.x : (p4 == 1) ? xcA0.z : (p4 == 2) ? xcA1.x : xcA1.z;
        xbA = (p4 == 0) ? xcA0.y : (p4 == 1) ? xcA0.w : (p4 == 2) ? xcA1.y : xcA1.w;
        xaB = (p4 == 0) ? xcB0.x : (p4 == 1) ? xcB0.z : (p4 == 2) ? xcB1.x : xcB1.z;
        xbB = (p4 == 0) ? xcB0.y : (p4 == 1) ? xcB0.w : (p4 == 2) ? xcB1.y : xcB1.w;
      } else {
        xaA = (p4 == 0) ? xcA1.w : (p4 == 1) ? xcA1.y : (p4 == 2) ? xcA0.w : xcA0.y;
        xbA = (p4 == 0) ? xcA1.z : (p4 == 1) ? xcA1.x : (p4 == 2) ? xcA0.z : xcA0.x;
        xaB = (p4 == 0) ? xcB1.w : (p4 == 1) ? xcB1.y : (p4 == 2) ? xcB0.w : xcB0.y;
        xbB = (p4 == 0) ? xcB1.z : (p4 == 1) ? xcB1.x : (p4 == 2) ? xcB0.z : xcB0.x;
      }
      s16x8 vhA = as_s16x8(vhiA), vlA = as_s16x8(vloA);
      s16x8 vhB = as_s16x8(vhiB), vlB = as_s16x8(vloB);

      // two independent 3-deep accumulator chains per sample-group, interleaved A/B
      f32x16 D1A = __builtin_amdgcn_mfma_f32_32x32x16_bf16(fr[p4*4+0], vhA, Dz, 0, 0, 0);
      f32x16 D1B = __builtin_amdgcn_mfma_f32_32x32x16_bf16(fr[p4*4+0], vhB, Dz, 0, 0, 0);
      f32x16 D2A = __builtin_amdgcn_mfma_f32_32x32x16_bf16(fr[p4*4+2], vhA, Dz, 0, 0, 0);
      f32x16 D2B = __builtin_amdgcn_mfma_f32_32x32x16_bf16(fr[p4*4+2], vhB, Dz, 0, 0, 0);
      D1A = __builtin_amdgcn_mfma_f32_32x32x16_bf16(fr[p4*4+0], vlA, D1A, 0, 0, 0);
      D1B = __builtin_amdgcn_mfma_f32_32x32x16_bf16(fr[p4*4+0], vlB, D1B, 0, 0, 0);
      D2A = __builtin_amdgcn_mfma_f32_32x32x16_bf16(fr[p4*4+2], vlA, D2A, 0, 0, 0);
      D2B = __builtin_amdgcn_mfma_f32_32x32x16_bf16(fr[p4*4+2], vlB, D2B, 0, 0, 0);
      D1A = __builtin_amdgcn_mfma_f32_32x32x16_bf16(fr[p4*4+1], vhA, D1A, 0, 0, 0);
      D1B = __builtin_amdgcn_mfma_f32_32x32x16_bf16(fr[p4*4+1], vhB, D1B, 0, 0, 0);
      D2A = __builtin_amdgcn_mfma_f32_32x32x16_bf16(fr[p4*4+3], vhA, D2A, 0, 0, 0);
      D2B = __builtin_amdgcn_mfma_f32_32x32x16_bf16(fr[p4*4+3], vhB, D2B, 0, 0, 0);

#pragma unroll
      for (int r = 0; r < 8; ++r)
        dcombA[r] = fmaf(xbA, fmaf(xaA, D2A[r+8], D2A[r]), fmaf(xaA, D1A[r+8], D1A[r]));
      split_pack8(dcombA, vhiA, vloA);          // tau-permuted A: already natural order
#pragma unroll
      for (int r = 0; r < 8; ++r)
        dcombB[r] = fmaf(xbB, fmaf(xaB, D2B[r+8], D2B[r]), fmaf(xaB, D1B[r+8], D1B[r]));
      split_pack8(dcombB, vhiB, vloB);
    }
    asm volatile("s_waitcnt vmcnt(0)" ::: "memory");
    xcA0 = xnA0; xcA1 = xnA1; xcB0 = xnB0; xcB1 = xnB1;
  }

  // final f32 states (natural row order thanks to tau) -> LDS
#pragma unroll
  for (int r = 0; r < 8; ++r) {
    fin[side][col][h*8 + r]      = dcombA[r];
    fin[side][col + 32][h*8 + r] = dcombB[r];
  }
  __syncthreads();

  // head: y = c0 + v^T M u, 2 threads per sample
  {
    int s = tidx >> 1, j = tidx & 1;
    const float* Mf = reinterpret_cast<const float*>(ws) + 262144;
    float c0 = reinterpret_cast<const float*>(ws)[262400];
    float acc = 0.f;
#pragma unroll
    for (int dd = 0; dd < 8; ++dd) {
      int d = j*8 + dd;
      float zd = 0.f;
#pragma unroll
      for (int e = 0; e < 16; ++e) zd = fmaf(Mf[d*16 + e], fin[1][s][e], zd);
      acc = fmaf(fin[0][s][d], zd, acc);
    }
    acc += __shfl_xor(acc, 1, 64);
    if (j == 0) out[blockIdx.x*64 + s] = acc + c0;
  }
}

extern "C" void kernel_launch(void* const* d_in, const int* in_sizes, int n_in,
                              void* d_out, int out_size, void* d_ws, size_t ws_size,
                              hipStream_t stream)
{
  const float* x       = (const float*)d_in[0];
  const float* W0      = (const float*)d_in[1];
  const float* W_left  = (const float*)d_in[2];
  const float* W_out   = (const float*)d_in[3];
  const float* W_right = (const float*)d_in[4];
  const float* WN      = (const float*)d_in[5];
  const float* d1_w    = (const float*)d_in[6];
  const float* d1_b    = (const float*)d_in[7];
  const float* d2_w    = (const float*)d_in[8];
  const float* d2_b    = (const float*)d_in[9];
  unsigned short* ws   = (unsigned short*)d_ws;
  float* out           = (float*)d_out;

  if (ws_size < (size_t)WS_BYTES_NEEDED) return;

  hipLaunchKernelGGL(mps_prep, dim3(257), dim3(256), 0, stream,
                     W0, W_left, W_out, W_right, WN, d1_w, d1_b, d2_w, d2_b, ws);
  hipLaunchKernelGGL(mps_main, dim3(256), dim3(128), 0, stream,
                     x, W0, WN, ws, out);
}

// Round 6
// 61.983 us; speedup vs baseline: 1.4937x; 1.4937x over previous
//
#include <hip/hip_runtime.h>
#include <stdint.h>

#define B_N    16384
#define F_N    512
#define NPAIR  128            // 256 steps (1 pad + 255 sites) fused into 128 pairs per side
#define CHUNKP 4              // pairs per staged chunk
#define NCHUNKC (NPAIR/CHUNKP)

typedef float    f32x4  __attribute__((ext_vector_type(4)));
typedef short    s16x8  __attribute__((ext_vector_type(8)));
typedef int      i32x4  __attribute__((ext_vector_type(4)));
typedef unsigned u32x2  __attribute__((ext_vector_type(2)));

// ws layout (shorts): left pair-frags [0,262144), right [262144,524288),
// M (256 f32) at short 524288, c0 at short 524800.
// per pair-side: 2048 shorts = [A1hi(512)|A1lo(512)|A2hi(512)|A2lo(512)]
#define WS_SIDE_STRIDE 262144
#define WS_BYTES_NEEDED ((524800 + 2) * 2)

// pack 4 floats -> 2 packed-bf16 hi words + 2 lo words (trunc split)
static __device__ __forceinline__ void split4(const float* f, unsigned* ph, unsigned* pl) {
#pragma unroll
  for (int j = 0; j < 2; ++j) {
    float f0 = f[2*j], f1 = f[2*j+1];
    unsigned u0 = __float_as_uint(f0), u1 = __float_as_uint(f1);
    ph[j] = __builtin_amdgcn_perm(u1, u0, 0x07060302u);
    float l0 = f0 - __uint_as_float(u0 & 0xffff0000u);
    float l1 = f1 - __uint_as_float(u1 & 0xffff0000u);
    pl[j] = __builtin_amdgcn_perm(__float_as_uint(l1), __float_as_uint(l0), 0x07060302u);
  }
}

// 8 floats -> 4 hi words + 4 lo words. split4 consumes 4 floats / writes 2 words:
// call on f[0..3] and f[4..7].  (Round-5 bug was f+2/ph+1 here.)
static __device__ __forceinline__ void split_pack8(const float* f, unsigned* ph, unsigned* pl) {
  split4(f,     ph,     pl);
  split4(f + 4, ph + 2, pl + 2);
}

// swap32: lo lanes -> (a_own, a_from_hi); hi lanes -> (b_from_lo, b_own)
static __device__ __forceinline__ void swap32p(unsigned a, unsigned b, unsigned &x, unsigned &y) {
#if __has_builtin(__builtin_amdgcn_permlane32_swap)
  u32x2 r = __builtin_amdgcn_permlane32_swap(a, b, false, false);
  x = (unsigned)r.x; y = (unsigned)r.y;
#else
  unsigned oa = (unsigned)__shfl_xor((int)a, 32, 64);
  unsigned ob = (unsigned)__shfl_xor((int)b, 32, 64);
  bool hi = (threadIdx.x & 32) != 0;
  x = hi ? ob : a;
  y = hi ? b  : oa;
#endif
}

static __device__ __forceinline__ s16x8 as_s16x8(const unsigned* p) {
  i32x4 v; v.x = (int)p[0]; v.y = (int)p[1]; v.z = (int)p[2]; v.w = (int)p[3];
  return __builtin_bit_cast(s16x8, v);
}

// tau: swap bits 2<->3 of a 4-bit row index
static __device__ __forceinline__ int tau(int m) {
  return (m & 3) | ((m & 4) << 1) | ((m & 8) >> 1);
}

// ---------------- prep: fuse site pairs, emit 16x16x32 K-stacked MFMA A-frags ----------
// Left pair p: v'' = sum_{i,j} xa^i xb^j P_ij^T v, P_ij = Wa_i * Wb_j.
//   A1 = [P00^T | P10^T] (K-stacked 16x32), A2 = [P01^T | P11^T]; applied to vv=[v; xa v].
// Right pair p: u'' = sum R_ij xa^i xb^j u, R_ij = Wb_j * Wa_i; A1 = [R00|R10], A2 = [R01|R11].
// A rows stored tau-permuted so D lane-group G holds natural rows {0,8,4,12}[G]+0..3.
// Frag layout: lane l holds A[m=l&15][k=8*(l>>4)+i], i=0..7.
__global__ __launch_bounds__(256) void mps_prep(
    const float* __restrict__ W0, const float* __restrict__ W_left,
    const float* __restrict__ W_out, const float* __restrict__ W_right,
    const float* __restrict__ WN, const float* __restrict__ d1_w,
    const float* __restrict__ d1_b, const float* __restrict__ d2_w,
    const float* __restrict__ d2_b, unsigned short* __restrict__ ws)
{
  int bid = blockIdx.x;
  if (bid < 256) {
    int side = bid >> 7;
    int pair = bid & 127;
    __shared__ float Wa[512];    // [d*32 + p*16 + m]
    __shared__ float Wb[512];
    __shared__ float Af[1024];   // [amat][pa*16+mm][k]: left P_{pa,amat}[k][tau(mm)], right R_{pa,amat}[tau(mm)][k]
    int t = threadIdx.x;
    bool pad_a = (pair == 0);
    const float* base_a = side ? (W_right + (size_t)(255 - 2*pair) * 512)
                               : (W_left  + (size_t)(2*pair - 1) * 512);
    const float* base_b = side ? (W_right + (size_t)(254 - 2*pair) * 512)
                               : (W_left  + (size_t)(2*pair) * 512);
#pragma unroll
    for (int e = t; e < 512; e += 256) {
      float va;
      if (pad_a) { int d = e >> 5, p = (e >> 4) & 1, m = e & 15; va = (p == 0 && d == m) ? 1.f : 0.f; }
      else va = base_a[e];
      Wa[e] = va;
      Wb[e] = base_b[e];
    }
    __syncthreads();
#pragma unroll
    for (int ei = t; ei < 1024; ei += 256) {
      int amat = ei >> 9;          // phys idx of site b
      int rem  = ei & 511;
      int m32  = rem >> 4;
      int k    = rem & 15;
      int pa   = m32 >> 4;         // phys idx of site a
      int m    = tau(m32 & 15);    // tau-permuted output row
      float acc = 0.f;
      if (side == 0) {
#pragma unroll
        for (int j = 0; j < 16; ++j) acc += Wa[k*32 + pa*16 + j] * Wb[j*32 + amat*16 + m];
      } else {
#pragma unroll
        for (int j = 0; j < 16; ++j) acc += Wb[m*32 + amat*16 + j] * Wa[j*32 + pa*16 + k];
      }
      Af[ei] = acc;
    }
    __syncthreads();
    {
      int f = t >> 6, l = t & 63;          // f: 0=A1hi 1=A1lo 2=A2hi 3=A2lo
      int amat = f >> 1, lo = f & 1;
      int m = l & 15, kb = (l >> 4) * 8;
      s16x8 v8;
#pragma unroll
      for (int i = 0; i < 8; ++i) {
        int k = kb + i;
        float w = Af[amat*512 + ((k >> 4)*16 + m)*16 + (k & 15)];
        unsigned u = __float_as_uint(w);
        unsigned short h = (unsigned short)(u >> 16);
        if (lo) {
          float rl = w - __uint_as_float((unsigned)h << 16);
          h = (unsigned short)(__float_as_uint(rl) >> 16);
        }
        v8[i] = (short)h;
      }
      *reinterpret_cast<s16x8*>(ws + (size_t)side * WS_SIDE_STRIDE
                                   + (size_t)pair * 2048 + f * 512 + l * 8) = v8;
    }
  } else {
    // M[d][e] = sum_o wef[o] * W_out[d][o][e];  c0 = d2_b + sum_h d2_w[h] d1_b[h]
    int t = threadIdx.x;
    int d = t >> 4, e = t & 15;
    float acc = 0.f;
#pragma unroll
    for (int o = 0; o < 8; ++o) {
      float wef = 0.f;
      for (int hh = 0; hh < 24; ++hh) wef += d2_w[hh] * d1_w[hh*8 + o];
      acc += wef * W_out[d*128 + o*16 + e];
    }
    float* wf = reinterpret_cast<float*>(ws);
    wf[262144 + t] = acc;
    if (t == 0) {
      float c0 = d2_b[0];
      for (int hh = 0; hh < 24; ++hh) c0 += d2_w[hh] * d1_b[hh];
      wf[262400] = c0;
    }
  }
}

// ---------------- main: 512 blocks x 4 waves {L0,L1,R0,R1}, 16 samples/wave, 2 waves/SIMD
__global__ __launch_bounds__(256, 2) void mps_main(
    const float* __restrict__ x, const float* __restrict__ W0,
    const float* __restrict__ WN, const unsigned short* __restrict__ ws,
    float* __restrict__ out)
{
  __shared__ __align__(16) unsigned short sbuf[2][2][CHUNKP][4][64][8]; // 64 KiB
  __shared__ float fin[2][32][16];                                      // 4 KiB

  const int tidx = threadIdx.x;
  const int wave = tidx >> 6;
  const int lane = tidx & 63;
  const int side = wave >> 1;
  const int q    = wave & 1;
  const int n    = lane & 15;         // sample column
  const int g    = lane >> 4;         // lane group (k-range 8g..8g+7)
  const int b    = blockIdx.x * 32 + q * 16 + n;
  const float* xrow = x + (size_t)b * F_N;
  const unsigned short* frag = ws + (size_t)side * WS_SIDE_STRIDE;
  const int rbase = ((g & 1) << 3) | ((g & 2) << 1);   // D natural-row base: 0,8,4,12

  // init B-operand for pair 0 directly: vv = [v0 ; xa*v0]
  unsigned bw[4], bwl[4];
  {
    float xi0 = side ? xrow[F_N-1] : xrow[0];
    float f8[8];
#pragma unroll
    for (int i = 0; i < 8; ++i) {
      int k = g*8 + i;
      int j = k & 15;
      float a0 = side ? WN[j*2]   : W0[j];
      float a1 = side ? WN[j*2+1] : W0[16+j];
      float v0 = fmaf(xi0, a1, a0);
      f8[i] = (g >= 2) ? xi0 * v0 : v0;    // pad's xa multiplies zero matrix; value irrelevant
    }
    split_pack8(f8, bw, bwl);
  }

  f32x4 Dz = {0.f, 0.f, 0.f, 0.f};

  auto stage = [&](int chunk, int db) {
    const unsigned short* gs = frag + (size_t)chunk * (CHUNKP * 2048);
#pragma unroll
    for (int s2 = 0; s2 < 8; ++s2) {
      int idx = q*8 + s2;
      int pr = idx >> 2, fg = idx & 3;
      __builtin_amdgcn_global_load_lds(
        (const __attribute__((address_space(1))) void*)(gs + pr*2048 + fg*512 + lane*8),
        (__attribute__((address_space(3))) void*)(&sbuf[side][db][pr][fg][0][0]),
        16, 0, 0);
    }
  };

  auto xp0 = [&](int c) { return xrow + (side ? (504 - 8*c) : (8*c)); };
  auto xp1 = [&](int c) { return xrow + (side ? (508 - 8*c) : (8*c + 4)); };

  float4 xc0 = *reinterpret_cast<const float4*>(xp0(0));
  float4 xc1 = *reinterpret_cast<const float4*>(xp1(0));

  stage(0, 0);
  asm volatile("s_waitcnt vmcnt(0)" ::: "memory");
  __syncthreads();

  float st[4];
#pragma unroll 1
  for (int c = 0; c < NCHUNKC; ++c) {
    float4 xn0 = xc0, xn1 = xc1;
    if (c + 1 < NCHUNKC) {
      stage(c + 1, (c + 1) & 1);
      xn0 = *reinterpret_cast<const float4*>(xp0(c + 1));
      xn1 = *reinterpret_cast<const float4*>(xp1(c + 1));
    }
    const unsigned short* lb = &sbuf[side][c & 1][0][0][0][0];

    float xa[5], xb[4];
    if (side == 0) {
      xa[0]=xc0.x; xa[1]=xc0.z; xa[2]=xc1.x; xa[3]=xc1.z; xa[4]=xn0.x;
      xb[0]=xc0.y; xb[1]=xc0.w; xb[2]=xc1.y; xb[3]=xc1.w;
    } else {
      xa[0]=xc1.w; xa[1]=xc1.y; xa[2]=xc0.w; xa[3]=xc0.y; xa[4]=xn1.w;
      xb[0]=xc1.z; xb[1]=xc1.x; xb[2]=xc0.z; xb[3]=xc0.x;
    }

#pragma unroll
    for (int pr = 0; pr < 4; ++pr) {
      s16x8 a1h = *reinterpret_cast<const s16x8*>(lb + pr*2048 + 0*512 + lane*8);
      s16x8 a1l = *reinterpret_cast<const s16x8*>(lb + pr*2048 + 1*512 + lane*8);
      s16x8 a2h = *reinterpret_cast<const s16x8*>(lb + pr*2048 + 2*512 + lane*8);
      s16x8 a2l = *reinterpret_cast<const s16x8*>(lb + pr*2048 + 3*512 + lane*8);
      s16x8 Bh = as_s16x8(bw), Bl = as_s16x8(bwl);

      // two parallel 3-deep acc chains
      f32x4 D1 = __builtin_amdgcn_mfma_f32_16x16x32_bf16(a1h, Bh, Dz, 0, 0, 0);
      f32x4 D2 = __builtin_amdgcn_mfma_f32_16x16x32_bf16(a2h, Bh, Dz, 0, 0, 0);
      D1 = __builtin_amdgcn_mfma_f32_16x16x32_bf16(a1h, Bl, D1, 0, 0, 0);
      D2 = __builtin_amdgcn_mfma_f32_16x16x32_bf16(a2h, Bl, D2, 0, 0, 0);
      D1 = __builtin_amdgcn_mfma_f32_16x16x32_bf16(a1l, Bh, D1, 0, 0, 0);
      D2 = __builtin_amdgcn_mfma_f32_16x16x32_bf16(a2l, Bh, D2, 0, 0, 0);

#pragma unroll
      for (int r = 0; r < 4; ++r) st[r] = fmaf(xb[pr], D2[r], D1[r]);

      // build next B: split, then 2 swap32 per precision
      float xs[4];
#pragma unroll
      for (int r = 0; r < 4; ++r) xs[r] = xa[pr + 1] * st[r];
      unsigned vh2[2], vl2[2], xh2[2], xl2[2];
      split4(st, vh2, vl2);
      split4(xs, xh2, xl2);
      swap32p(vh2[0], xh2[0], bw[0], bw[2]);
      swap32p(vh2[1], xh2[1], bw[1], bw[3]);
      swap32p(vl2[0], xl2[0], bwl[0], bwl[2]);
      swap32p(vl2[1], xl2[1], bwl[1], bwl[3]);
    }
    asm volatile("s_waitcnt vmcnt(0)" ::: "memory");
    __syncthreads();
    xc0 = xn0; xc1 = xn1;
  }

  // final f32 state (natural rows rbase..rbase+3) -> LDS
#pragma unroll
  for (int r = 0; r < 4; ++r) fin[side][q*16 + n][rbase + r] = st[r];
  __syncthreads();

  // head: y = c0 + v^T M u, 8 threads per sample
  {
    int s = tidx >> 3, j = tidx & 7;
    const float* Mf = reinterpret_cast<const float*>(ws) + 262144;
    float c0 = reinterpret_cast<const float*>(ws)[262400];
    float acc = 0.f;
#pragma unroll
    for (int dd = 0; dd < 2; ++dd) {
      int d = j*2 + dd;
      float zd = 0.f;
#pragma unroll
      for (int e = 0; e < 16; ++e) zd = fmaf(Mf[d*16 + e], fin[1][s][e], zd);
      acc = fmaf(fin[0][s][d], zd, acc);
    }
    acc += __shfl_xor(acc, 1, 64);
    acc += __shfl_xor(acc, 2, 64);
    acc += __shfl_xor(acc, 4, 64);
    if (j == 0) out[blockIdx.x*32 + s] = acc + c0;
  }
}

extern "C" void kernel_launch(void* const* d_in, const int* in_sizes, int n_in,
                              void* d_out, int out_size, void* d_ws, size_t ws_size,
                              hipStream_t stream)
{
  const float* x       = (const float*)d_in[0];
  const float* W0      = (const float*)d_in[1];
  const float* W_left  = (const float*)d_in[2];
  const float* W_out   = (const float*)d_in[3];
  const float* W_right = (const float*)d_in[4];
  const float* WN      = (const float*)d_in[5];
  const float* d1_w    = (const float*)d_in[6];
  const float* d1_b    = (const float*)d_in[7];
  const float* d2_w    = (const float*)d_in[8];
  const float* d2_b    = (const float*)d_in[9];
  unsigned short* ws   = (unsigned short*)d_ws;
  float* out           = (float*)d_out;

  if (ws_size < (size_t)WS_BYTES_NEEDED) return;

  hipLaunchKernelGGL(mps_prep, dim3(257), dim3(256), 0, stream,
                     W0, W_left, W_out, W_right, WN, d1_w, d1_b, d2_w, d2_b, ws);
  hipLaunchKernelGGL(mps_main, dim3(B_N/32), dim3(256), 0, stream,
                     x, W0, WN, ws, out);
}